// Round 1
// baseline (909.801 us; speedup 1.0000x reference)
//
#include <hip/hip_runtime.h>
#include <hip/hip_bf16.h>

#define N_USERS 40000
#define N_ITEMS 60000
#define N_NODES 100000
#define DIM 64
#define NNZ 1200000
#define BATCH 1024
#define NEG_SLOPE 0.2f

// ---------------- CSR build ----------------

__global__ void k_zero(int* __restrict__ p, int n) {
    int i = blockIdx.x * blockDim.x + threadIdx.x;
    if (i < n) p[i] = 0;
}

__global__ void k_count(const int* __restrict__ rows, int* __restrict__ counts) {
    int e = blockIdx.x * blockDim.x + threadIdx.x;
    if (e < NNZ) atomicAdd(&counts[rows[e]], 1);
}

// per-chunk (1024 elems) sums
__global__ void k_scanA(const int* __restrict__ counts, int* __restrict__ blk) {
    __shared__ int s[256];
    int base = blockIdx.x * 1024;
    int t = threadIdx.x;
    int sum = 0;
#pragma unroll
    for (int j = 0; j < 4; j++) {
        int i = base + t * 4 + j;
        if (i < N_NODES) sum += counts[i];
    }
    s[t] = sum;
    __syncthreads();
    for (int off = 128; off > 0; off >>= 1) {
        if (t < off) s[t] += s[t + off];
        __syncthreads();
    }
    if (t == 0) blk[blockIdx.x] = s[0];
}

// exclusive scan of chunk sums (in place), single thread (98 elems, negligible)
__global__ void k_scanB(int* __restrict__ blk, int nblk, int* __restrict__ row_ptr) {
    if (blockIdx.x == 0 && threadIdx.x == 0) {
        int run = 0;
        for (int b = 0; b < nblk; b++) {
            int v = blk[b];
            blk[b] = run;
            run += v;
        }
        row_ptr[N_NODES] = run;  // == NNZ
    }
}

// local scan + chunk offset -> row_ptr, cursors
__global__ void k_scanC(const int* __restrict__ counts, const int* __restrict__ blk,
                        int* __restrict__ row_ptr, int* __restrict__ cursors) {
    __shared__ int s[256];
    int base = blockIdx.x * 1024;
    int t = threadIdx.x;
    int local[4];
    int sum = 0;
#pragma unroll
    for (int j = 0; j < 4; j++) {
        int i = base + t * 4 + j;
        int v = (i < N_NODES) ? counts[i] : 0;
        local[j] = v;
        sum += v;
    }
    s[t] = sum;
    __syncthreads();
    // Hillis-Steele inclusive scan over 256 thread sums
    for (int off = 1; off < 256; off <<= 1) {
        int v = (t >= off) ? s[t - off] : 0;
        __syncthreads();
        s[t] += v;
        __syncthreads();
    }
    int excl = s[t] - sum + blk[blockIdx.x];
#pragma unroll
    for (int j = 0; j < 4; j++) {
        int i = base + t * 4 + j;
        if (i < N_NODES) {
            row_ptr[i] = excl;
            cursors[i] = excl;
            excl += local[j];
        }
    }
}

__global__ void k_scatter(const int* __restrict__ rows, const int* __restrict__ cols,
                          const float* __restrict__ vals, int* __restrict__ cursors,
                          int* __restrict__ scol, float* __restrict__ sval) {
    int e = blockIdx.x * blockDim.x + threadIdx.x;
    if (e < NNZ) {
        int r = rows[e];
        int p = atomicAdd(&cursors[r], 1);
        scol[p] = cols[e];
        sval[p] = vals[e];
    }
}

// ---------------- graph propagation ----------------

__global__ void k_initE(const float4* __restrict__ ue, const float4* __restrict__ ie,
                        float4* __restrict__ E) {
    int i = blockIdx.x * blockDim.x + threadIdx.x;  // float4 index
    const int UQ = N_USERS * DIM / 4;   // 640000
    const int TQ = N_NODES * DIM / 4;   // 1600000
    if (i < UQ) E[i] = ue[i];
    else if (i < TQ) E[i] = ie[i - UQ];
}

// gather-side SpMM: one wave per row, lane = dim
__global__ __launch_bounds__(256) void k_spmm(const float* __restrict__ E,
                                              const int* __restrict__ rp,
                                              const int* __restrict__ scol,
                                              const float* __restrict__ sval,
                                              float* __restrict__ Egc) {
    int gid = blockIdx.x * blockDim.x + threadIdx.x;
    int r = gid >> 6, lane = gid & 63;
    if (r >= N_NODES) return;
    int s = rp[r], e = rp[r + 1];
    float acc = 0.f;
    for (int j = s; j < e; j++) {
        acc = fmaf(sval[j], E[(size_t)scol[j] * DIM + lane], acc);
    }
    Egc[(size_t)r * DIM + lane] = acc;
}

// fused: side1=(E+Egc)@W1 + side2=(E*Egc)@W2 -> leaky_relu -> l2norm, in-place E
__global__ __launch_bounds__(256) void k_transform(float* __restrict__ E,
                                                   const float* __restrict__ Egc,
                                                   const float* __restrict__ W1,
                                                   const float* __restrict__ W2) {
    __shared__ float w1[DIM * DIM];
    __shared__ float w2[DIM * DIM];
    __shared__ float sa[4][DIM];
    __shared__ float sb[4][DIM];
    int t = threadIdx.x;
    for (int i = t; i < DIM * DIM; i += 256) {
        w1[i] = W1[i];
        w2[i] = W2[i];
    }
    int w = t >> 6, lane = t & 63;
    size_t r = (size_t)blockIdx.x * 4 + w;
    float e = E[r * DIM + lane];
    float g = Egc[r * DIM + lane];
    sa[w][lane] = e + g;
    sb[w][lane] = e * g;
    __syncthreads();
    float acc = 0.f;
#pragma unroll
    for (int k = 0; k < DIM; k++) {
        acc = fmaf(sa[w][k], w1[k * DIM + lane], acc);
        acc = fmaf(sb[w][k], w2[k * DIM + lane], acc);
    }
    acc = acc > 0.f ? acc : NEG_SLOPE * acc;
    float ss = acc * acc;
#pragma unroll
    for (int off = 1; off < 64; off <<= 1) ss += __shfl_xor(ss, off);
    float n = sqrtf(ss);
    E[r * DIM + lane] = acc / fmaxf(n, 1e-12f);
}

// gather batch rows into u/i feature blocks
__global__ void k_gather(const float* __restrict__ E, const int* __restrict__ uids,
                         const int* __restrict__ iids, float* __restrict__ uf,
                         float* __restrict__ inf, int col0) {
    int gid = blockIdx.x * blockDim.x + threadIdx.x;
    int row = gid >> 6, lane = gid & 63;
    if (row < BATCH) {
        uf[row * 256 + col0 + lane] = E[(size_t)uids[row] * DIM + lane];
    } else if (row < 2 * BATCH) {
        int r = row - BATCH;
        inf[r * 256 + col0 + lane] = E[(size_t)(N_USERS + iids[r]) * DIM + lane];
    }
}

// ---------------- final scores: out = U @ I^T, [1024,256] x [1024,256]^T ----------------

__global__ __launch_bounds__(256) void k_score(const float* __restrict__ uf,
                                               const float* __restrict__ inf,
                                               float* __restrict__ out) {
    __shared__ float su[32][68];
    __shared__ float si[32][68];
    int t = threadIdx.x;
    int bx = blockIdx.x & 15, by = blockIdx.x >> 4;
    int tx = t & 15, ty = t >> 4;
    int lrow = t >> 2;         // 0..63
    int lk = (t & 3) * 8;      // 0,8,16,24
    float acc[4][4] = {};
    for (int kk = 0; kk < 256; kk += 32) {
        float4 a0 = *(const float4*)&uf[(by * 64 + lrow) * 256 + kk + lk];
        float4 a1 = *(const float4*)&uf[(by * 64 + lrow) * 256 + kk + lk + 4];
        float4 b0 = *(const float4*)&inf[(bx * 64 + lrow) * 256 + kk + lk];
        float4 b1 = *(const float4*)&inf[(bx * 64 + lrow) * 256 + kk + lk + 4];
        __syncthreads();
        su[lk + 0][lrow] = a0.x; su[lk + 1][lrow] = a0.y;
        su[lk + 2][lrow] = a0.z; su[lk + 3][lrow] = a0.w;
        su[lk + 4][lrow] = a1.x; su[lk + 5][lrow] = a1.y;
        su[lk + 6][lrow] = a1.z; su[lk + 7][lrow] = a1.w;
        si[lk + 0][lrow] = b0.x; si[lk + 1][lrow] = b0.y;
        si[lk + 2][lrow] = b0.z; si[lk + 3][lrow] = b0.w;
        si[lk + 4][lrow] = b1.x; si[lk + 5][lrow] = b1.y;
        si[lk + 6][lrow] = b1.z; si[lk + 7][lrow] = b1.w;
        __syncthreads();
#pragma unroll
        for (int k = 0; k < 32; k++) {
            const float* pu = &su[k][ty * 4];
            const float* pi = &si[k][tx * 4];
#pragma unroll
            for (int mi = 0; mi < 4; mi++)
#pragma unroll
                for (int ni = 0; ni < 4; ni++)
                    acc[mi][ni] = fmaf(pu[mi], pi[ni], acc[mi][ni]);
        }
    }
#pragma unroll
    for (int mi = 0; mi < 4; mi++)
#pragma unroll
        for (int ni = 0; ni < 4; ni++)
            out[(size_t)(by * 64 + ty * 4 + mi) * 1024 + bx * 64 + tx * 4 + ni] = acc[mi][ni];
}

// ---------------- launch ----------------

extern "C" void kernel_launch(void* const* d_in, const int* in_sizes, int n_in,
                              void* d_out, int out_size, void* d_ws, size_t ws_size,
                              hipStream_t stream) {
    const float* user_embed = (const float*)d_in[0];
    const float* item_embed = (const float*)d_in[1];
    const float* W1[3] = {(const float*)d_in[2], (const float*)d_in[3], (const float*)d_in[4]};
    const float* W2[3] = {(const float*)d_in[5], (const float*)d_in[6], (const float*)d_in[7]};
    const float* adj_vals = (const float*)d_in[8];
    const int* adj_rows = (const int*)d_in[9];
    const int* adj_cols = (const int*)d_in[10];
    const int* user_ids = (const int*)d_in[11];
    const int* item_ids = (const int*)d_in[12];
    float* out = (float*)d_out;

    // workspace carve-up (all 16B-aligned)
    float* E = (float*)d_ws;                       // 6.4M f32
    float* Egc = E + (size_t)N_NODES * DIM;        // 6.4M f32
    float* uf = Egc + (size_t)N_NODES * DIM;       // 256K f32
    float* inf = uf + BATCH * 256;                 // 256K f32
    float* sval = inf + BATCH * 256;               // 1.2M f32
    int* scol = (int*)(sval + NNZ);                // 1.2M i32
    int* row_ptr = scol + NNZ;                     // 100001
    int* cursors = row_ptr + (N_NODES + 1);        // 100000
    int* counts = cursors + N_NODES;               // 100000
    int* blk = counts + N_NODES;                   // 128

    const int NBLK = (N_NODES + 1023) / 1024;  // 98

    // CSR build
    k_zero<<<(N_NODES + 255) / 256, 256, 0, stream>>>(counts, N_NODES);
    k_count<<<(NNZ + 255) / 256, 256, 0, stream>>>(adj_rows, counts);
    k_scanA<<<NBLK, 256, 0, stream>>>(counts, blk);
    k_scanB<<<1, 64, 0, stream>>>(blk, NBLK, row_ptr);
    k_scanC<<<NBLK, 256, 0, stream>>>(counts, blk, row_ptr, cursors);
    k_scatter<<<(NNZ + 255) / 256, 256, 0, stream>>>(adj_rows, adj_cols, adj_vals,
                                                     cursors, scol, sval);

    // E init + layer-0 gather
    k_initE<<<(N_NODES * DIM / 4 + 255) / 256, 256, 0, stream>>>(
        (const float4*)user_embed, (const float4*)item_embed, (float4*)E);
    k_gather<<<(2 * BATCH * DIM) / 256, 256, 0, stream>>>(E, user_ids, item_ids, uf, inf, 0);

    // 3 propagation layers
    for (int l = 0; l < 3; l++) {
        k_spmm<<<(N_NODES * DIM) / 256, 256, 0, stream>>>(E, row_ptr, scol, sval, Egc);
        k_transform<<<N_NODES / 4, 256, 0, stream>>>(E, Egc, W1[l], W2[l]);
        k_gather<<<(2 * BATCH * DIM) / 256, 256, 0, stream>>>(E, user_ids, item_ids, uf, inf,
                                                              (l + 1) * 64);
    }

    // scores
    k_score<<<256, 256, 0, stream>>>(uf, inf, out);
}

// Round 3
// 639.126 us; speedup vs baseline: 1.4235x; 1.4235x over previous
//
#include <hip/hip_runtime.h>
#include <hip/hip_bf16.h>

#define N_USERS 40000
#define N_ITEMS 60000
#define N_NODES 100000
#define DIM 64
#define NNZ 1200000
#define BATCH 1024
#define NEG_SLOPE 0.2f

// ---------------- CSR build ----------------

__global__ void k_zero(int* __restrict__ p, int n) {
    int i = blockIdx.x * blockDim.x + threadIdx.x;
    if (i < n) p[i] = 0;
}

__global__ void k_count(const int* __restrict__ rows, int* __restrict__ counts) {
    int e = blockIdx.x * blockDim.x + threadIdx.x;
    if (e < NNZ) atomicAdd(&counts[rows[e]], 1);
}

// per-chunk (1024 elems) sums
__global__ void k_scanA(const int* __restrict__ counts, int* __restrict__ blk) {
    __shared__ int s[256];
    int base = blockIdx.x * 1024;
    int t = threadIdx.x;
    int sum = 0;
#pragma unroll
    for (int j = 0; j < 4; j++) {
        int i = base + t * 4 + j;
        if (i < N_NODES) sum += counts[i];
    }
    s[t] = sum;
    __syncthreads();
    for (int off = 128; off > 0; off >>= 1) {
        if (t < off) s[t] += s[t + off];
        __syncthreads();
    }
    if (t == 0) blk[blockIdx.x] = s[0];
}

// exclusive scan of chunk sums (parallel, one 128-thread block; nblk=98)
__global__ void k_scanB(int* __restrict__ blk, int nblk, int* __restrict__ row_ptr) {
    __shared__ int s[128];
    int t = threadIdx.x;
    int v = (t < nblk) ? blk[t] : 0;
    s[t] = v;
    __syncthreads();
    for (int off = 1; off < 128; off <<= 1) {
        int x = (t >= off) ? s[t - off] : 0;
        __syncthreads();
        s[t] += x;
        __syncthreads();
    }
    if (t < nblk) blk[t] = s[t] - v;  // exclusive
    if (t == 0) row_ptr[N_NODES] = s[nblk - 1];  // total == NNZ
}

// local scan + chunk offset -> row_ptr, cursors
__global__ void k_scanC(const int* __restrict__ counts, const int* __restrict__ blk,
                        int* __restrict__ row_ptr, int* __restrict__ cursors) {
    __shared__ int s[256];
    int base = blockIdx.x * 1024;
    int t = threadIdx.x;
    int local[4];
    int sum = 0;
#pragma unroll
    for (int j = 0; j < 4; j++) {
        int i = base + t * 4 + j;
        int v = (i < N_NODES) ? counts[i] : 0;
        local[j] = v;
        sum += v;
    }
    s[t] = sum;
    __syncthreads();
    for (int off = 1; off < 256; off <<= 1) {
        int v2 = (t >= off) ? s[t - off] : 0;
        __syncthreads();
        s[t] += v2;
        __syncthreads();
    }
    int excl = s[t] - sum + blk[blockIdx.x];
#pragma unroll
    for (int j = 0; j < 4; j++) {
        int i = base + t * 4 + j;
        if (i < N_NODES) {
            row_ptr[i] = excl;
            cursors[i] = excl;
            excl += local[j];
        }
    }
}

__global__ void k_scatter(const int* __restrict__ rows, const int* __restrict__ cols,
                          const float* __restrict__ vals, int* __restrict__ cursors,
                          int* __restrict__ scol, float* __restrict__ sval) {
    int e = blockIdx.x * blockDim.x + threadIdx.x;
    if (e < NNZ) {
        int r = rows[e];
        int p = atomicAdd(&cursors[r], 1);
        scol[p] = cols[e];
        sval[p] = vals[e];
    }
}

// ---------------- propagation (fused SpMM + transform) ----------------

__global__ void k_initE(const float4* __restrict__ ue, const float4* __restrict__ ie,
                        float4* __restrict__ E) {
    int i = blockIdx.x * blockDim.x + threadIdx.x;  // float4 index
    const int UQ = N_USERS * DIM / 4;   // 640000
    const int TQ = N_NODES * DIM / 4;   // 1600000
    if (i < UQ) E[i] = ue[i];
    else if (i < TQ) E[i] = ie[i - UQ];
}

// One wave per row: gather-SpMM (4x unrolled) -> (E+g)@W1 + (E*g)@W2 -> lrelu -> l2norm.
// Persistent blocks: W1/W2 staged in LDS once per block. Double-buffered E (no in-place race).
__global__ __launch_bounds__(256) void k_layer(const float* __restrict__ Ein,
                                               float* __restrict__ Eout,
                                               const int* __restrict__ rp,
                                               const int* __restrict__ scol,
                                               const float* __restrict__ sval,
                                               const float* __restrict__ W1,
                                               const float* __restrict__ W2) {
    __shared__ float w1[DIM * DIM];
    __shared__ float w2[DIM * DIM];
    __shared__ float sa[4][DIM];
    __shared__ float sb[4][DIM];
    int t = threadIdx.x;
    for (int i = t; i < DIM * DIM; i += 256) {
        w1[i] = W1[i];
        w2[i] = W2[i];
    }
    __syncthreads();
    int w = t >> 6, lane = t & 63;
    const int NGRP = N_NODES / 4;  // 25000
    for (int grp = blockIdx.x; grp < NGRP; grp += gridDim.x) {
        int r = grp * 4 + w;
        int s = rp[r], e = rp[r + 1];
        float acc = 0.f;
        int j = s;
        for (; j + 4 <= e; j += 4) {
            int c0 = scol[j], c1 = scol[j + 1], c2 = scol[j + 2], c3 = scol[j + 3];
            float v0 = sval[j], v1 = sval[j + 1], v2 = sval[j + 2], v3 = sval[j + 3];
            float e0 = Ein[(size_t)c0 * DIM + lane];
            float e1 = Ein[(size_t)c1 * DIM + lane];
            float e2 = Ein[(size_t)c2 * DIM + lane];
            float e3 = Ein[(size_t)c3 * DIM + lane];
            acc = fmaf(v0, e0, acc);
            acc = fmaf(v1, e1, acc);
            acc = fmaf(v2, e2, acc);
            acc = fmaf(v3, e3, acc);
        }
        for (; j < e; j++) acc = fmaf(sval[j], Ein[(size_t)scol[j] * DIM + lane], acc);
        float ee = Ein[(size_t)r * DIM + lane];
        // wave-internal LDS exchange (each wave owns sa[w]/sb[w]; no cross-wave barrier needed)
        sa[w][lane] = ee + acc;
        sb[w][lane] = ee * acc;
        float o = 0.f;
#pragma unroll
        for (int k = 0; k < DIM; k++) {
            o = fmaf(sa[w][k], w1[k * DIM + lane], o);
            o = fmaf(sb[w][k], w2[k * DIM + lane], o);
        }
        o = o > 0.f ? o : NEG_SLOPE * o;
        float ss = o * o;
#pragma unroll
        for (int off = 1; off < 64; off <<= 1) ss += __shfl_xor(ss, off);
        Eout[(size_t)r * DIM + lane] = o / fmaxf(sqrtf(ss), 1e-12f);
    }
}

// gather batch rows into u/i feature blocks
__global__ void k_gather(const float* __restrict__ E, const int* __restrict__ uids,
                         const int* __restrict__ iids, float* __restrict__ uf,
                         float* __restrict__ inf, int col0) {
    int gid = blockIdx.x * blockDim.x + threadIdx.x;
    int row = gid >> 6, lane = gid & 63;
    if (row < BATCH) {
        uf[row * 256 + col0 + lane] = E[(size_t)uids[row] * DIM + lane];
    } else if (row < 2 * BATCH) {
        int r = row - BATCH;
        inf[r * 256 + col0 + lane] = E[(size_t)(N_USERS + iids[r]) * DIM + lane];
    }
}

// ---------------- final scores: out = U @ I^T, [1024,256] x [1024,256]^T ----------------

__global__ __launch_bounds__(256) void k_score(const float* __restrict__ uf,
                                               const float* __restrict__ inf,
                                               float* __restrict__ out) {
    __shared__ float su[32][68];
    __shared__ float si[32][68];
    int t = threadIdx.x;
    int bx = blockIdx.x & 15, by = blockIdx.x >> 4;
    int tx = t & 15, ty = t >> 4;
    int lrow = t >> 2;         // 0..63
    int lk = (t & 3) * 8;      // 0,8,16,24
    float acc[4][4] = {};
    for (int kk = 0; kk < 256; kk += 32) {
        float4 a0 = *(const float4*)&uf[(by * 64 + lrow) * 256 + kk + lk];
        float4 a1 = *(const float4*)&uf[(by * 64 + lrow) * 256 + kk + lk + 4];
        float4 b0 = *(const float4*)&inf[(bx * 64 + lrow) * 256 + kk + lk];
        float4 b1 = *(const float4*)&inf[(bx * 64 + lrow) * 256 + kk + lk + 4];
        __syncthreads();
        su[lk + 0][lrow] = a0.x; su[lk + 1][lrow] = a0.y;
        su[lk + 2][lrow] = a0.z; su[lk + 3][lrow] = a0.w;
        su[lk + 4][lrow] = a1.x; su[lk + 5][lrow] = a1.y;
        su[lk + 6][lrow] = a1.z; su[lk + 7][lrow] = a1.w;
        si[lk + 0][lrow] = b0.x; si[lk + 1][lrow] = b0.y;
        si[lk + 2][lrow] = b0.z; si[lk + 3][lrow] = b0.w;
        si[lk + 4][lrow] = b1.x; si[lk + 5][lrow] = b1.y;
        si[lk + 6][lrow] = b1.z; si[lk + 7][lrow] = b1.w;
        __syncthreads();
#pragma unroll
        for (int k = 0; k < 32; k++) {
            const float* pu = &su[k][ty * 4];
            const float* pi = &si[k][tx * 4];
#pragma unroll
            for (int mi = 0; mi < 4; mi++)
#pragma unroll
                for (int ni = 0; ni < 4; ni++)
                    acc[mi][ni] = fmaf(pu[mi], pi[ni], acc[mi][ni]);
        }
    }
#pragma unroll
    for (int mi = 0; mi < 4; mi++)
#pragma unroll
        for (int ni = 0; ni < 4; ni++)
            out[(size_t)(by * 64 + ty * 4 + mi) * 1024 + bx * 64 + tx * 4 + ni] = acc[mi][ni];
}

// ---------------- launch ----------------

extern "C" void kernel_launch(void* const* d_in, const int* in_sizes, int n_in,
                              void* d_out, int out_size, void* d_ws, size_t ws_size,
                              hipStream_t stream) {
    const float* user_embed = (const float*)d_in[0];
    const float* item_embed = (const float*)d_in[1];
    const float* W1[3] = {(const float*)d_in[2], (const float*)d_in[3], (const float*)d_in[4]};
    const float* W2[3] = {(const float*)d_in[5], (const float*)d_in[6], (const float*)d_in[7]};
    const float* adj_vals = (const float*)d_in[8];
    const int* adj_rows = (const int*)d_in[9];
    const int* adj_cols = (const int*)d_in[10];
    const int* user_ids = (const int*)d_in[11];
    const int* item_ids = (const int*)d_in[12];
    float* out = (float*)d_out;

    // workspace carve-up (all 16B-aligned)
    float* E0 = (float*)d_ws;                      // 6.4M f32
    float* E1 = E0 + (size_t)N_NODES * DIM;        // 6.4M f32
    float* uf = E1 + (size_t)N_NODES * DIM;        // 256K f32
    float* inf = uf + BATCH * 256;                 // 256K f32
    float* sval = inf + BATCH * 256;               // 1.2M f32
    int* scol = (int*)(sval + NNZ);                // 1.2M i32
    int* row_ptr = scol + NNZ;                     // 100001
    int* cursors = row_ptr + (N_NODES + 1);        // 100000
    int* counts = cursors + N_NODES;               // 100000
    int* blk = counts + N_NODES;                   // 128

    const int NBLK = (N_NODES + 1023) / 1024;  // 98

    // CSR build
    k_zero<<<(N_NODES + 255) / 256, 256, 0, stream>>>(counts, N_NODES);
    k_count<<<(NNZ + 255) / 256, 256, 0, stream>>>(adj_rows, counts);
    k_scanA<<<NBLK, 256, 0, stream>>>(counts, blk);
    k_scanB<<<1, 128, 0, stream>>>(blk, NBLK, row_ptr);
    k_scanC<<<NBLK, 256, 0, stream>>>(counts, blk, row_ptr, cursors);
    k_scatter<<<(NNZ + 255) / 256, 256, 0, stream>>>(adj_rows, adj_cols, adj_vals,
                                                     cursors, scol, sval);

    // E init + layer-0 gather
    k_initE<<<(N_NODES * DIM / 4 + 255) / 256, 256, 0, stream>>>(
        (const float4*)user_embed, (const float4*)item_embed, (float4*)E0);
    k_gather<<<(2 * BATCH * DIM) / 256, 256, 0, stream>>>(E0, user_ids, item_ids, uf, inf, 0);

    // 3 fused propagation layers, ping-pong E0/E1
    float* bufs[2] = {E0, E1};
    for (int l = 0; l < 3; l++) {
        const float* Ein = bufs[l & 1];
        float* Eout = bufs[(l + 1) & 1];
        k_layer<<<1024, 256, 0, stream>>>(Ein, Eout, row_ptr, scol, sval, W1[l], W2[l]);
        k_gather<<<(2 * BATCH * DIM) / 256, 256, 0, stream>>>(Eout, user_ids, item_ids, uf, inf,
                                                              (l + 1) * 64);
    }

    // scores
    k_score<<<256, 256, 0, stream>>>(uf, inf, out);
}

// Round 5
// 620.896 us; speedup vs baseline: 1.4653x; 1.0294x over previous
//
#include <hip/hip_runtime.h>
#include <hip/hip_bf16.h>

#define N_USERS 40000
#define N_ITEMS 60000
#define N_NODES 100000
#define DIM 64
#define NNZ 1200000
#define BATCH 1024
#define NEG_SLOPE 0.2f

// ---------------- CSR build ----------------

__global__ void k_zero(int* __restrict__ p, int n) {
    int i = blockIdx.x * blockDim.x + threadIdx.x;
    if (i < n) p[i] = 0;
}

__global__ void k_count(const int* __restrict__ rows, int* __restrict__ counts) {
    int e = blockIdx.x * blockDim.x + threadIdx.x;
    if (e < NNZ) atomicAdd(&counts[rows[e]], 1);
}

// per-chunk (1024 elems) sums
__global__ void k_scanA(const int* __restrict__ counts, int* __restrict__ blk) {
    __shared__ int s[256];
    int base = blockIdx.x * 1024;
    int t = threadIdx.x;
    int sum = 0;
#pragma unroll
    for (int j = 0; j < 4; j++) {
        int i = base + t * 4 + j;
        if (i < N_NODES) sum += counts[i];
    }
    s[t] = sum;
    __syncthreads();
    for (int off = 128; off > 0; off >>= 1) {
        if (t < off) s[t] += s[t + off];
        __syncthreads();
    }
    if (t == 0) blk[blockIdx.x] = s[0];
}

// exclusive scan of chunk sums (parallel, one 128-thread block; nblk=98)
__global__ void k_scanB(int* __restrict__ blk, int nblk, int* __restrict__ row_ptr) {
    __shared__ int s[128];
    int t = threadIdx.x;
    int v = (t < nblk) ? blk[t] : 0;
    s[t] = v;
    __syncthreads();
    for (int off = 1; off < 128; off <<= 1) {
        int x = (t >= off) ? s[t - off] : 0;
        __syncthreads();
        s[t] += x;
        __syncthreads();
    }
    if (t < nblk) blk[t] = s[t] - v;  // exclusive
    if (t == 0) row_ptr[N_NODES] = s[nblk - 1];  // total == NNZ
}

// local scan + chunk offset -> row_ptr, cursors
__global__ void k_scanC(const int* __restrict__ counts, const int* __restrict__ blk,
                        int* __restrict__ row_ptr, int* __restrict__ cursors) {
    __shared__ int s[256];
    int base = blockIdx.x * 1024;
    int t = threadIdx.x;
    int local[4];
    int sum = 0;
#pragma unroll
    for (int j = 0; j < 4; j++) {
        int i = base + t * 4 + j;
        int v = (i < N_NODES) ? counts[i] : 0;
        local[j] = v;
        sum += v;
    }
    s[t] = sum;
    __syncthreads();
    for (int off = 1; off < 256; off <<= 1) {
        int v2 = (t >= off) ? s[t - off] : 0;
        __syncthreads();
        s[t] += v2;
        __syncthreads();
    }
    int excl = s[t] - sum + blk[blockIdx.x];
#pragma unroll
    for (int j = 0; j < 4; j++) {
        int i = base + t * 4 + j;
        if (i < N_NODES) {
            row_ptr[i] = excl;
            cursors[i] = excl;
            excl += local[j];
        }
    }
}

// scatter (col, val) packed as int2: one 8B store per edge
__global__ void k_scatter(const int* __restrict__ rows, const int* __restrict__ cols,
                          const float* __restrict__ vals, int* __restrict__ cursors,
                          int2* __restrict__ edges) {
    int e = blockIdx.x * blockDim.x + threadIdx.x;
    if (e < NNZ) {
        int r = rows[e];
        int p = atomicAdd(&cursors[r], 1);
        edges[p] = make_int2(cols[e], __float_as_int(vals[e]));
    }
}

// ---------------- propagation ----------------

__global__ void k_initE(const float4* __restrict__ ue, const float4* __restrict__ ie,
                        float4* __restrict__ E) {
    int i = blockIdx.x * blockDim.x + threadIdx.x;  // float4 index
    const int UQ = N_USERS * DIM / 4;   // 640000
    const int TQ = N_NODES * DIM / 4;   // 1600000
    if (i < UQ) E[i] = ue[i];
    else if (i < TQ) E[i] = ie[i - UQ];
}

// gather-side SpMM: one wave per row, lane = dim; 8/4/1 unroll for MLP.
__global__ __launch_bounds__(256) void k_spmm(const float* __restrict__ Ein,
                                              const int* __restrict__ rp,
                                              const int2* __restrict__ edges,
                                              float* __restrict__ Egc) {
    int gid = blockIdx.x * blockDim.x + threadIdx.x;
    int r = gid >> 6, lane = gid & 63;
    if (r >= N_NODES) return;
    int s = rp[r], e = rp[r + 1];
    float acc = 0.f;
    int j = s;
    for (; j + 8 <= e; j += 8) {
        int2 q0 = edges[j], q1 = edges[j + 1], q2 = edges[j + 2], q3 = edges[j + 3];
        int2 q4 = edges[j + 4], q5 = edges[j + 5], q6 = edges[j + 6], q7 = edges[j + 7];
        float f0 = Ein[(size_t)q0.x * DIM + lane];
        float f1 = Ein[(size_t)q1.x * DIM + lane];
        float f2 = Ein[(size_t)q2.x * DIM + lane];
        float f3 = Ein[(size_t)q3.x * DIM + lane];
        float f4 = Ein[(size_t)q4.x * DIM + lane];
        float f5 = Ein[(size_t)q5.x * DIM + lane];
        float f6 = Ein[(size_t)q6.x * DIM + lane];
        float f7 = Ein[(size_t)q7.x * DIM + lane];
        acc = fmaf(__int_as_float(q0.y), f0, acc);
        acc = fmaf(__int_as_float(q1.y), f1, acc);
        acc = fmaf(__int_as_float(q2.y), f2, acc);
        acc = fmaf(__int_as_float(q3.y), f3, acc);
        acc = fmaf(__int_as_float(q4.y), f4, acc);
        acc = fmaf(__int_as_float(q5.y), f5, acc);
        acc = fmaf(__int_as_float(q6.y), f6, acc);
        acc = fmaf(__int_as_float(q7.y), f7, acc);
    }
    for (; j + 4 <= e; j += 4) {
        int2 q0 = edges[j], q1 = edges[j + 1], q2 = edges[j + 2], q3 = edges[j + 3];
        float f0 = Ein[(size_t)q0.x * DIM + lane];
        float f1 = Ein[(size_t)q1.x * DIM + lane];
        float f2 = Ein[(size_t)q2.x * DIM + lane];
        float f3 = Ein[(size_t)q3.x * DIM + lane];
        acc = fmaf(__int_as_float(q0.y), f0, acc);
        acc = fmaf(__int_as_float(q1.y), f1, acc);
        acc = fmaf(__int_as_float(q2.y), f2, acc);
        acc = fmaf(__int_as_float(q3.y), f3, acc);
    }
    for (; j < e; j++) {
        int2 q = edges[j];
        acc = fmaf(__int_as_float(q.y), Ein[(size_t)q.x * DIM + lane], acc);
    }
    Egc[(size_t)r * DIM + lane] = acc;
}

// registerized transform: W1/W2 columns in VGPRs, row broadcast via readlane.
// In-place on E (row-local). Zero LDS in the inner loop.
__global__ __launch_bounds__(256) void k_transform(float* __restrict__ E,
                                                   const float* __restrict__ Egc,
                                                   const float* __restrict__ W1,
                                                   const float* __restrict__ W2) {
    int t = threadIdx.x;
    int lane = t & 63;
    int wv = t >> 6;
    float w1c[DIM], w2c[DIM];
#pragma unroll
    for (int k = 0; k < DIM; k++) {
        w1c[k] = W1[k * DIM + lane];
        w2c[k] = W2[k * DIM + lane];
    }
    int wgid = blockIdx.x * 4 + wv;
    int nw = gridDim.x * 4;
    for (int r = wgid; r < N_NODES; r += nw) {
        float e = E[(size_t)r * DIM + lane];
        float g = Egc[(size_t)r * DIM + lane];
        float xa = e + g;
        float xb = e * g;
        float o = 0.f;
#pragma unroll
        for (int k = 0; k < DIM; k++) {
            float a = __int_as_float(__builtin_amdgcn_readlane(__float_as_int(xa), k));
            float b = __int_as_float(__builtin_amdgcn_readlane(__float_as_int(xb), k));
            o = fmaf(a, w1c[k], o);
            o = fmaf(b, w2c[k], o);
        }
        o = o > 0.f ? o : NEG_SLOPE * o;
        float ss = o * o;
#pragma unroll
        for (int off = 1; off < 64; off <<= 1) ss += __shfl_xor(ss, off);
        E[(size_t)r * DIM + lane] = o / fmaxf(sqrtf(ss), 1e-12f);
    }
}

// gather batch rows into u/i feature blocks
__global__ void k_gather(const float* __restrict__ E, const int* __restrict__ uids,
                         const int* __restrict__ iids, float* __restrict__ uf,
                         float* __restrict__ inf, int col0) {
    int gid = blockIdx.x * blockDim.x + threadIdx.x;
    int row = gid >> 6, lane = gid & 63;
    if (row < BATCH) {
        uf[row * 256 + col0 + lane] = E[(size_t)uids[row] * DIM + lane];
    } else if (row < 2 * BATCH) {
        int r = row - BATCH;
        inf[r * 256 + col0 + lane] = E[(size_t)(N_USERS + iids[r]) * DIM + lane];
    }
}

// ---------------- final scores: out = U @ I^T, [1024,256] x [1024,256]^T ----------------

__global__ __launch_bounds__(256) void k_score(const float* __restrict__ uf,
                                               const float* __restrict__ inf,
                                               float* __restrict__ out) {
    __shared__ float su[32][68];
    __shared__ float si[32][68];
    int t = threadIdx.x;
    int bx = blockIdx.x & 15, by = blockIdx.x >> 4;
    int tx = t & 15, ty = t >> 4;
    int lrow = t >> 2;         // 0..63
    int lk = (t & 3) * 8;      // 0,8,16,24
    float acc[4][4] = {};
    for (int kk = 0; kk < 256; kk += 32) {
        float4 a0 = *(const float4*)&uf[(by * 64 + lrow) * 256 + kk + lk];
        float4 a1 = *(const float4*)&uf[(by * 64 + lrow) * 256 + kk + lk + 4];
        float4 b0 = *(const float4*)&inf[(bx * 64 + lrow) * 256 + kk + lk];
        float4 b1 = *(const float4*)&inf[(bx * 64 + lrow) * 256 + kk + lk + 4];
        __syncthreads();
        su[lk + 0][lrow] = a0.x; su[lk + 1][lrow] = a0.y;
        su[lk + 2][lrow] = a0.z; su[lk + 3][lrow] = a0.w;
        su[lk + 4][lrow] = a1.x; su[lk + 5][lrow] = a1.y;
        su[lk + 6][lrow] = a1.z; su[lk + 7][lrow] = a1.w;
        si[lk + 0][lrow] = b0.x; si[lk + 1][lrow] = b0.y;
        si[lk + 2][lrow] = b0.z; si[lk + 3][lrow] = b0.w;
        si[lk + 4][lrow] = b1.x; si[lk + 5][lrow] = b1.y;
        si[lk + 6][lrow] = b1.z; si[lk + 7][lrow] = b1.w;
        __syncthreads();
#pragma unroll
        for (int k = 0; k < 32; k++) {
            const float* pu = &su[k][ty * 4];
            const float* pi = &si[k][tx * 4];
#pragma unroll
            for (int mi = 0; mi < 4; mi++)
#pragma unroll
                for (int ni = 0; ni < 4; ni++)
                    acc[mi][ni] = fmaf(pu[mi], pi[ni], acc[mi][ni]);
        }
    }
#pragma unroll
    for (int mi = 0; mi < 4; mi++)
#pragma unroll
        for (int ni = 0; ni < 4; ni++)
            out[(size_t)(by * 64 + ty * 4 + mi) * 1024 + bx * 64 + tx * 4 + ni] = acc[mi][ni];
}

// ---------------- launch ----------------

extern "C" void kernel_launch(void* const* d_in, const int* in_sizes, int n_in,
                              void* d_out, int out_size, void* d_ws, size_t ws_size,
                              hipStream_t stream) {
    const float* user_embed = (const float*)d_in[0];
    const float* item_embed = (const float*)d_in[1];
    const float* W1[3] = {(const float*)d_in[2], (const float*)d_in[3], (const float*)d_in[4]};
    const float* W2[3] = {(const float*)d_in[5], (const float*)d_in[6], (const float*)d_in[7]};
    const float* adj_vals = (const float*)d_in[8];
    const int* adj_rows = (const int*)d_in[9];
    const int* adj_cols = (const int*)d_in[10];
    const int* user_ids = (const int*)d_in[11];
    const int* item_ids = (const int*)d_in[12];
    float* out = (float*)d_out;

    // workspace carve-up (all 16B-aligned)
    float* E = (float*)d_ws;                       // 6.4M f32
    float* Egc = E + (size_t)N_NODES * DIM;        // 6.4M f32
    float* uf = Egc + (size_t)N_NODES * DIM;       // 256K f32
    float* inf = uf + BATCH * 256;                 // 256K f32
    int2* edges = (int2*)(inf + BATCH * 256);      // 1.2M int2
    int* row_ptr = (int*)(edges + NNZ);            // 100001
    int* cursors = row_ptr + (N_NODES + 1);        // 100000
    int* counts = cursors + N_NODES;               // 100000
    int* blk = counts + N_NODES;                   // 128

    const int NBLK = (N_NODES + 1023) / 1024;  // 98

    // CSR build
    k_zero<<<(N_NODES + 255) / 256, 256, 0, stream>>>(counts, N_NODES);
    k_count<<<(NNZ + 255) / 256, 256, 0, stream>>>(adj_rows, counts);
    k_scanA<<<NBLK, 256, 0, stream>>>(counts, blk);
    k_scanB<<<1, 128, 0, stream>>>(blk, NBLK, row_ptr);
    k_scanC<<<NBLK, 256, 0, stream>>>(counts, blk, row_ptr, cursors);
    k_scatter<<<(NNZ + 255) / 256, 256, 0, stream>>>(adj_rows, adj_cols, adj_vals,
                                                     cursors, edges);

    // E init + layer-0 gather
    k_initE<<<(N_NODES * DIM / 4 + 255) / 256, 256, 0, stream>>>(
        (const float4*)user_embed, (const float4*)item_embed, (float4*)E);
    k_gather<<<(2 * BATCH * DIM) / 256, 256, 0, stream>>>(E, user_ids, item_ids, uf, inf, 0);

    // 3 propagation layers (spmm -> registerized transform in-place -> gather)
    for (int l = 0; l < 3; l++) {
        k_spmm<<<(N_NODES * DIM) / 256, 256, 0, stream>>>(E, row_ptr, edges, Egc);
        k_transform<<<768, 256, 0, stream>>>(E, Egc, W1[l], W2[l]);
        k_gather<<<(2 * BATCH * DIM) / 256, 256, 0, stream>>>(E, user_ids, item_ids, uf, inf,
                                                              (l + 1) * 64);
    }

    // scores
    k_score<<<256, 256, 0, stream>>>(uf, inf, out);
}

// Round 6
// 593.498 us; speedup vs baseline: 1.5329x; 1.0462x over previous
//
#include <hip/hip_runtime.h>
#include <hip/hip_bf16.h>

#define N_USERS 40000
#define N_ITEMS 60000
#define N_NODES 100000
#define DIM 64
#define NNZ 1200000
#define BATCH 1024
#define NEG_SLOPE 0.2f
#define NPART 8
#define PROWS ((N_NODES + NPART - 1) / NPART)  // 12500

// ---------------- CSR build ----------------

__global__ void k_zero(int* __restrict__ p, int n) {
    int i = blockIdx.x * blockDim.x + threadIdx.x;
    if (i < n) p[i] = 0;
}

// XCD-partitioned histogram: blocks with blockIdx&7==p own row range [p*PROWS, (p+1)*PROWS).
// All partitions scan all edges (rows[] replicated reads served by L3); atomics stay XCD-local.
__global__ __launch_bounds__(256) void k_count(const int* __restrict__ rows,
                                               int* __restrict__ counts) {
    int p = blockIdx.x & (NPART - 1);
    int chunk = blockIdx.x >> 3;
    int nchunk = gridDim.x >> 3;
    int per = (NNZ + nchunk - 1) / nchunk;
    int lo = chunk * per;
    int hi = min(lo + per, NNZ);
    int rlo = p * PROWS, rhi = rlo + PROWS;
    for (int e = lo + (int)threadIdx.x; e < hi; e += 256) {
        int r = rows[e];
        if (r >= rlo && r < rhi) atomicAdd(&counts[r], 1);
    }
}

// per-chunk (1024 elems) sums
__global__ void k_scanA(const int* __restrict__ counts, int* __restrict__ blk) {
    __shared__ int s[256];
    int base = blockIdx.x * 1024;
    int t = threadIdx.x;
    int sum = 0;
#pragma unroll
    for (int j = 0; j < 4; j++) {
        int i = base + t * 4 + j;
        if (i < N_NODES) sum += counts[i];
    }
    s[t] = sum;
    __syncthreads();
    for (int off = 128; off > 0; off >>= 1) {
        if (t < off) s[t] += s[t + off];
        __syncthreads();
    }
    if (t == 0) blk[blockIdx.x] = s[0];
}

// exclusive scan of chunk sums (parallel, one 128-thread block; nblk=98)
__global__ void k_scanB(int* __restrict__ blk, int nblk, int* __restrict__ row_ptr) {
    __shared__ int s[128];
    int t = threadIdx.x;
    int v = (t < nblk) ? blk[t] : 0;
    s[t] = v;
    __syncthreads();
    for (int off = 1; off < 128; off <<= 1) {
        int x = (t >= off) ? s[t - off] : 0;
        __syncthreads();
        s[t] += x;
        __syncthreads();
    }
    if (t < nblk) blk[t] = s[t] - v;  // exclusive
    if (t == 0) row_ptr[N_NODES] = s[nblk - 1];  // total == NNZ
}

// local scan + chunk offset -> row_ptr, cursors
__global__ void k_scanC(const int* __restrict__ counts, const int* __restrict__ blk,
                        int* __restrict__ row_ptr, int* __restrict__ cursors) {
    __shared__ int s[256];
    int base = blockIdx.x * 1024;
    int t = threadIdx.x;
    int local[4];
    int sum = 0;
#pragma unroll
    for (int j = 0; j < 4; j++) {
        int i = base + t * 4 + j;
        int v = (i < N_NODES) ? counts[i] : 0;
        local[j] = v;
        sum += v;
    }
    s[t] = sum;
    __syncthreads();
    for (int off = 1; off < 256; off <<= 1) {
        int v2 = (t >= off) ? s[t - off] : 0;
        __syncthreads();
        s[t] += v2;
        __syncthreads();
    }
    int excl = s[t] - sum + blk[blockIdx.x];
#pragma unroll
    for (int j = 0; j < 4; j++) {
        int i = base + t * 4 + j;
        if (i < N_NODES) {
            row_ptr[i] = excl;
            cursors[i] = excl;
            excl += local[j];
        }
    }
}

// XCD-partitioned scatter: same ownership scheme as k_count. Each partition's
// destination range in edges[] is contiguous (CSR offsets sorted by row), so
// dirty lines stay within one XCD's L2 -> writeback ~= 9.6MB once, not 8x.
__global__ __launch_bounds__(256) void k_scatter(const int* __restrict__ rows,
                                                 const int* __restrict__ cols,
                                                 const float* __restrict__ vals,
                                                 int* __restrict__ cursors,
                                                 int2* __restrict__ edges) {
    int p = blockIdx.x & (NPART - 1);
    int chunk = blockIdx.x >> 3;
    int nchunk = gridDim.x >> 3;
    int per = (NNZ + nchunk - 1) / nchunk;
    int lo = chunk * per;
    int hi = min(lo + per, NNZ);
    int rlo = p * PROWS, rhi = rlo + PROWS;
    for (int e = lo + (int)threadIdx.x; e < hi; e += 256) {
        int r = rows[e];
        if (r >= rlo && r < rhi) {
            int pos = atomicAdd(&cursors[r], 1);
            edges[pos] = make_int2(cols[e], __float_as_int(vals[e]));
        }
    }
}

// ---------------- propagation ----------------

__global__ void k_initE(const float4* __restrict__ ue, const float4* __restrict__ ie,
                        float4* __restrict__ E) {
    int i = blockIdx.x * blockDim.x + threadIdx.x;  // float4 index
    const int UQ = N_USERS * DIM / 4;   // 640000
    const int TQ = N_NODES * DIM / 4;   // 1600000
    if (i < UQ) E[i] = ue[i];
    else if (i < TQ) E[i] = ie[i - UQ];
}

// gather-side SpMM: one wave per row; lane holds 2 dims (float2), lane halves
// (lane<32 / lane>=32) process even/odd edges concurrently -> 2 edges per step,
// 8 edges in flight in the unrolled loop. Cross-half combine via shfl_xor(32).
__global__ __launch_bounds__(256) void k_spmm(const float* __restrict__ Ein,
                                              const int* __restrict__ rp,
                                              const int2* __restrict__ edges,
                                              float* __restrict__ Egc) {
    int gid = blockIdx.x * blockDim.x + threadIdx.x;
    int r = gid >> 6, lane = gid & 63;
    if (r >= N_NODES) return;
    int half = lane >> 5, l32 = lane & 31;
    int s = rp[r], e = rp[r + 1];
    float2 acc = make_float2(0.f, 0.f);
    int j = s;
    for (; j + 8 <= e; j += 8) {
        int base = j + half * 4;
        int2 q0 = edges[base], q1 = edges[base + 1], q2 = edges[base + 2], q3 = edges[base + 3];
        float2 f0 = *(const float2*)&Ein[(size_t)q0.x * DIM + l32 * 2];
        float2 f1 = *(const float2*)&Ein[(size_t)q1.x * DIM + l32 * 2];
        float2 f2 = *(const float2*)&Ein[(size_t)q2.x * DIM + l32 * 2];
        float2 f3 = *(const float2*)&Ein[(size_t)q3.x * DIM + l32 * 2];
        float v0 = __int_as_float(q0.y), v1 = __int_as_float(q1.y);
        float v2 = __int_as_float(q2.y), v3 = __int_as_float(q3.y);
        acc.x = fmaf(v0, f0.x, acc.x); acc.y = fmaf(v0, f0.y, acc.y);
        acc.x = fmaf(v1, f1.x, acc.x); acc.y = fmaf(v1, f1.y, acc.y);
        acc.x = fmaf(v2, f2.x, acc.x); acc.y = fmaf(v2, f2.y, acc.y);
        acc.x = fmaf(v3, f3.x, acc.x); acc.y = fmaf(v3, f3.y, acc.y);
    }
    for (; j + 2 <= e; j += 2) {
        int2 q = edges[j + half];
        float2 f = *(const float2*)&Ein[(size_t)q.x * DIM + l32 * 2];
        float v = __int_as_float(q.y);
        acc.x = fmaf(v, f.x, acc.x);
        acc.y = fmaf(v, f.y, acc.y);
    }
    if (j < e && half == 0) {  // odd tail edge
        int2 q = edges[j];
        float2 f = *(const float2*)&Ein[(size_t)q.x * DIM + l32 * 2];
        float v = __int_as_float(q.y);
        acc.x = fmaf(v, f.x, acc.x);
        acc.y = fmaf(v, f.y, acc.y);
    }
    acc.x += __shfl_xor(acc.x, 32);
    acc.y += __shfl_xor(acc.y, 32);
    if (half == 0) *(float2*)&Egc[(size_t)r * DIM + l32 * 2] = acc;
}

// registerized transform: W1/W2 columns in VGPRs, row broadcast via readlane.
// In-place on E (row-local). Zero LDS in the inner loop.
__global__ __launch_bounds__(256) void k_transform(float* __restrict__ E,
                                                   const float* __restrict__ Egc,
                                                   const float* __restrict__ W1,
                                                   const float* __restrict__ W2) {
    int t = threadIdx.x;
    int lane = t & 63;
    int wv = t >> 6;
    float w1c[DIM], w2c[DIM];
#pragma unroll
    for (int k = 0; k < DIM; k++) {
        w1c[k] = W1[k * DIM + lane];
        w2c[k] = W2[k * DIM + lane];
    }
    int wgid = blockIdx.x * 4 + wv;
    int nw = gridDim.x * 4;
    for (int r = wgid; r < N_NODES; r += nw) {
        float e = E[(size_t)r * DIM + lane];
        float g = Egc[(size_t)r * DIM + lane];
        float xa = e + g;
        float xb = e * g;
        float o = 0.f;
#pragma unroll
        for (int k = 0; k < DIM; k++) {
            float a = __int_as_float(__builtin_amdgcn_readlane(__float_as_int(xa), k));
            float b = __int_as_float(__builtin_amdgcn_readlane(__float_as_int(xb), k));
            o = fmaf(a, w1c[k], o);
            o = fmaf(b, w2c[k], o);
        }
        o = o > 0.f ? o : NEG_SLOPE * o;
        float ss = o * o;
#pragma unroll
        for (int off = 1; off < 64; off <<= 1) ss += __shfl_xor(ss, off);
        E[(size_t)r * DIM + lane] = o / fmaxf(sqrtf(ss), 1e-12f);
    }
}

// gather batch rows into u/i feature blocks
__global__ void k_gather(const float* __restrict__ E, const int* __restrict__ uids,
                         const int* __restrict__ iids, float* __restrict__ uf,
                         float* __restrict__ inf, int col0) {
    int gid = blockIdx.x * blockDim.x + threadIdx.x;
    int row = gid >> 6, lane = gid & 63;
    if (row < BATCH) {
        uf[row * 256 + col0 + lane] = E[(size_t)uids[row] * DIM + lane];
    } else if (row < 2 * BATCH) {
        int r = row - BATCH;
        inf[r * 256 + col0 + lane] = E[(size_t)(N_USERS + iids[r]) * DIM + lane];
    }
}

// ---------------- final scores: out = U @ I^T, [1024,256] x [1024,256]^T ----------------

__global__ __launch_bounds__(256) void k_score(const float* __restrict__ uf,
                                               const float* __restrict__ inf,
                                               float* __restrict__ out) {
    __shared__ float su[32][68];
    __shared__ float si[32][68];
    int t = threadIdx.x;
    int bx = blockIdx.x & 15, by = blockIdx.x >> 4;
    int tx = t & 15, ty = t >> 4;
    int lrow = t >> 2;         // 0..63
    int lk = (t & 3) * 8;      // 0,8,16,24
    float acc[4][4] = {};
    for (int kk = 0; kk < 256; kk += 32) {
        float4 a0 = *(const float4*)&uf[(by * 64 + lrow) * 256 + kk + lk];
        float4 a1 = *(const float4*)&uf[(by * 64 + lrow) * 256 + kk + lk + 4];
        float4 b0 = *(const float4*)&inf[(bx * 64 + lrow) * 256 + kk + lk];
        float4 b1 = *(const float4*)&inf[(bx * 64 + lrow) * 256 + kk + lk + 4];
        __syncthreads();
        su[lk + 0][lrow] = a0.x; su[lk + 1][lrow] = a0.y;
        su[lk + 2][lrow] = a0.z; su[lk + 3][lrow] = a0.w;
        su[lk + 4][lrow] = a1.x; su[lk + 5][lrow] = a1.y;
        su[lk + 6][lrow] = a1.z; su[lk + 7][lrow] = a1.w;
        si[lk + 0][lrow] = b0.x; si[lk + 1][lrow] = b0.y;
        si[lk + 2][lrow] = b0.z; si[lk + 3][lrow] = b0.w;
        si[lk + 4][lrow] = b1.x; si[lk + 5][lrow] = b1.y;
        si[lk + 6][lrow] = b1.z; si[lk + 7][lrow] = b1.w;
        __syncthreads();
#pragma unroll
        for (int k = 0; k < 32; k++) {
            const float* pu = &su[k][ty * 4];
            const float* pi = &si[k][tx * 4];
#pragma unroll
            for (int mi = 0; mi < 4; mi++)
#pragma unroll
                for (int ni = 0; ni < 4; ni++)
                    acc[mi][ni] = fmaf(pu[mi], pi[ni], acc[mi][ni]);
        }
    }
#pragma unroll
    for (int mi = 0; mi < 4; mi++)
#pragma unroll
        for (int ni = 0; ni < 4; ni++)
            out[(size_t)(by * 64 + ty * 4 + mi) * 1024 + bx * 64 + tx * 4 + ni] = acc[mi][ni];
}

// ---------------- launch ----------------

extern "C" void kernel_launch(void* const* d_in, const int* in_sizes, int n_in,
                              void* d_out, int out_size, void* d_ws, size_t ws_size,
                              hipStream_t stream) {
    const float* user_embed = (const float*)d_in[0];
    const float* item_embed = (const float*)d_in[1];
    const float* W1[3] = {(const float*)d_in[2], (const float*)d_in[3], (const float*)d_in[4]};
    const float* W2[3] = {(const float*)d_in[5], (const float*)d_in[6], (const float*)d_in[7]};
    const float* adj_vals = (const float*)d_in[8];
    const int* adj_rows = (const int*)d_in[9];
    const int* adj_cols = (const int*)d_in[10];
    const int* user_ids = (const int*)d_in[11];
    const int* item_ids = (const int*)d_in[12];
    float* out = (float*)d_out;

    // workspace carve-up (all 16B-aligned)
    float* E = (float*)d_ws;                       // 6.4M f32
    float* Egc = E + (size_t)N_NODES * DIM;        // 6.4M f32
    float* uf = Egc + (size_t)N_NODES * DIM;       // 256K f32
    float* inf = uf + BATCH * 256;                 // 256K f32
    int2* edges = (int2*)(inf + BATCH * 256);      // 1.2M int2
    int* row_ptr = (int*)(edges + NNZ);            // 100001
    int* cursors = row_ptr + (N_NODES + 1);        // 100000
    int* counts = cursors + N_NODES;               // 100000
    int* blk = counts + N_NODES;                   // 128

    const int NBLK = (N_NODES + 1023) / 1024;  // 98

    // CSR build (count/scatter XCD-partitioned: grid 8 partitions x 128 chunks)
    k_zero<<<(N_NODES + 255) / 256, 256, 0, stream>>>(counts, N_NODES);
    k_count<<<1024, 256, 0, stream>>>(adj_rows, counts);
    k_scanA<<<NBLK, 256, 0, stream>>>(counts, blk);
    k_scanB<<<1, 128, 0, stream>>>(blk, NBLK, row_ptr);
    k_scanC<<<NBLK, 256, 0, stream>>>(counts, blk, row_ptr, cursors);
    k_scatter<<<1024, 256, 0, stream>>>(adj_rows, adj_cols, adj_vals, cursors, edges);

    // E init + layer-0 gather
    k_initE<<<(N_NODES * DIM / 4 + 255) / 256, 256, 0, stream>>>(
        (const float4*)user_embed, (const float4*)item_embed, (float4*)E);
    k_gather<<<(2 * BATCH * DIM) / 256, 256, 0, stream>>>(E, user_ids, item_ids, uf, inf, 0);

    // 3 propagation layers (spmm -> registerized transform in-place -> gather)
    for (int l = 0; l < 3; l++) {
        k_spmm<<<(N_NODES * DIM) / 256, 256, 0, stream>>>(E, row_ptr, edges, Egc);
        k_transform<<<768, 256, 0, stream>>>(E, Egc, W1[l], W2[l]);
        k_gather<<<(2 * BATCH * DIM) / 256, 256, 0, stream>>>(E, user_ids, item_ids, uf, inf,
                                                              (l + 1) * 64);
    }

    // scores
    k_score<<<256, 256, 0, stream>>>(uf, inf, out);
}

// Round 8
// 434.883 us; speedup vs baseline: 2.0921x; 1.3647x over previous
//
#include <hip/hip_runtime.h>
#include <hip/hip_bf16.h>
#include <hip/hip_fp16.h>

#define N_USERS 40000
#define N_ITEMS 60000
#define N_NODES 100000
#define NPAD 100032  // padded to 64-row blocks for MFMA transform
#define DIM 64
#define NNZ 1200000
#define BATCH 1024
#define NEG_SLOPE 0.2f
#define NPART 8
#define PROWS ((N_NODES + NPART - 1) / NPART)  // 12500

typedef _Float16 half8 __attribute__((ext_vector_type(8)));
typedef float f32x4 __attribute__((ext_vector_type(4)));

// ---------------- CSR build ----------------

__global__ void k_zero(int* __restrict__ p, int n) {
    int i = blockIdx.x * blockDim.x + threadIdx.x;
    if (i < n) p[i] = 0;
}

// XCD-partitioned histogram: blocks with blockIdx&7==p own row range [p*PROWS, (p+1)*PROWS).
__global__ __launch_bounds__(256) void k_count(const int* __restrict__ rows,
                                               int* __restrict__ counts) {
    int p = blockIdx.x & (NPART - 1);
    int chunk = blockIdx.x >> 3;
    int nchunk = gridDim.x >> 3;
    int per = (NNZ + nchunk - 1) / nchunk;
    int lo = chunk * per;
    int hi = min(lo + per, NNZ);
    int rlo = p * PROWS, rhi = rlo + PROWS;
    for (int e = lo + (int)threadIdx.x; e < hi; e += 256) {
        int r = rows[e];
        if (r >= rlo && r < rhi) atomicAdd(&counts[r], 1);
    }
}

// per-chunk (1024 elems) sums
__global__ void k_scanA(const int* __restrict__ counts, int* __restrict__ blk) {
    __shared__ int s[256];
    int base = blockIdx.x * 1024;
    int t = threadIdx.x;
    int sum = 0;
#pragma unroll
    for (int j = 0; j < 4; j++) {
        int i = base + t * 4 + j;
        if (i < N_NODES) sum += counts[i];
    }
    s[t] = sum;
    __syncthreads();
    for (int off = 128; off > 0; off >>= 1) {
        if (t < off) s[t] += s[t + off];
        __syncthreads();
    }
    if (t == 0) blk[blockIdx.x] = s[0];
}

// exclusive scan of chunk sums (parallel, one 128-thread block; nblk=98)
__global__ void k_scanB(int* __restrict__ blk, int nblk, int* __restrict__ row_ptr) {
    __shared__ int s[128];
    int t = threadIdx.x;
    int v = (t < nblk) ? blk[t] : 0;
    s[t] = v;
    __syncthreads();
    for (int off = 1; off < 128; off <<= 1) {
        int x = (t >= off) ? s[t - off] : 0;
        __syncthreads();
        s[t] += x;
        __syncthreads();
    }
    if (t < nblk) blk[t] = s[t] - v;  // exclusive
    if (t == 0) row_ptr[N_NODES] = s[nblk - 1];
}

// local scan + chunk offset -> row_ptr, cursors
__global__ void k_scanC(const int* __restrict__ counts, const int* __restrict__ blk,
                        int* __restrict__ row_ptr, int* __restrict__ cursors) {
    __shared__ int s[256];
    int base = blockIdx.x * 1024;
    int t = threadIdx.x;
    int local[4];
    int sum = 0;
#pragma unroll
    for (int j = 0; j < 4; j++) {
        int i = base + t * 4 + j;
        int v = (i < N_NODES) ? counts[i] : 0;
        local[j] = v;
        sum += v;
    }
    s[t] = sum;
    __syncthreads();
    for (int off = 1; off < 256; off <<= 1) {
        int v2 = (t >= off) ? s[t - off] : 0;
        __syncthreads();
        s[t] += v2;
        __syncthreads();
    }
    int excl = s[t] - sum + blk[blockIdx.x];
#pragma unroll
    for (int j = 0; j < 4; j++) {
        int i = base + t * 4 + j;
        if (i < N_NODES) {
            row_ptr[i] = excl;
            cursors[i] = excl;
            excl += local[j];
        }
    }
}

// XCD-partitioned scatter (same ownership scheme as k_count)
__global__ __launch_bounds__(256) void k_scatter(const int* __restrict__ rows,
                                                 const int* __restrict__ cols,
                                                 const float* __restrict__ vals,
                                                 int* __restrict__ cursors,
                                                 int2* __restrict__ edges) {
    int p = blockIdx.x & (NPART - 1);
    int chunk = blockIdx.x >> 3;
    int nchunk = gridDim.x >> 3;
    int per = (NNZ + nchunk - 1) / nchunk;
    int lo = chunk * per;
    int hi = min(lo + per, NNZ);
    int rlo = p * PROWS, rhi = rlo + PROWS;
    for (int e = lo + (int)threadIdx.x; e < hi; e += 256) {
        int r = rows[e];
        if (r >= rlo && r < rhi) {
            int pos = atomicAdd(&cursors[r], 1);
            edges[pos] = make_int2(cols[e], __float_as_int(vals[e]));
        }
    }
}

// ---------------- propagation ----------------

__global__ void k_initE(const float4* __restrict__ ue, const float4* __restrict__ ie,
                        float4* __restrict__ E, __half2* __restrict__ Eh2) {
    int i = blockIdx.x * blockDim.x + threadIdx.x;  // float4 index
    const int UQ = N_USERS * DIM / 4;   // 640000
    const int TQ = N_NODES * DIM / 4;   // 1600000
    float4 v;
    if (i < UQ) v = ue[i];
    else if (i < TQ) v = ie[i - UQ];
    else return;
    E[i] = v;
    Eh2[i * 2] = __floats2half2_rn(v.x, v.y);
    Eh2[i * 2 + 1] = __floats2half2_rn(v.z, v.w);
}

// gather-side SpMM over f16 E copy: one wave per row; lane holds 2 dims (half2),
// lane halves process even/odd edges concurrently; f32 accumulate.
__global__ __launch_bounds__(256) void k_spmm(const __half2* __restrict__ Eh2,
                                              const int* __restrict__ rp,
                                              const int2* __restrict__ edges,
                                              float* __restrict__ Egc) {
    int gid = blockIdx.x * blockDim.x + threadIdx.x;
    int r = gid >> 6, lane = gid & 63;
    if (r >= N_NODES) return;
    int half = lane >> 5, l32 = lane & 31;
    int s = rp[r], e = rp[r + 1];
    float2 acc = make_float2(0.f, 0.f);
    int j = s;
    for (; j + 8 <= e; j += 8) {
        int base = j + half * 4;
        int2 q0 = edges[base], q1 = edges[base + 1], q2 = edges[base + 2], q3 = edges[base + 3];
        float2 f0 = __half22float2(Eh2[(size_t)q0.x * 32 + l32]);
        float2 f1 = __half22float2(Eh2[(size_t)q1.x * 32 + l32]);
        float2 f2 = __half22float2(Eh2[(size_t)q2.x * 32 + l32]);
        float2 f3 = __half22float2(Eh2[(size_t)q3.x * 32 + l32]);
        float v0 = __int_as_float(q0.y), v1 = __int_as_float(q1.y);
        float v2 = __int_as_float(q2.y), v3 = __int_as_float(q3.y);
        acc.x = fmaf(v0, f0.x, acc.x); acc.y = fmaf(v0, f0.y, acc.y);
        acc.x = fmaf(v1, f1.x, acc.x); acc.y = fmaf(v1, f1.y, acc.y);
        acc.x = fmaf(v2, f2.x, acc.x); acc.y = fmaf(v2, f2.y, acc.y);
        acc.x = fmaf(v3, f3.x, acc.x); acc.y = fmaf(v3, f3.y, acc.y);
    }
    for (; j + 2 <= e; j += 2) {
        int2 q = edges[j + half];
        float2 f = __half22float2(Eh2[(size_t)q.x * 32 + l32]);
        float v = __int_as_float(q.y);
        acc.x = fmaf(v, f.x, acc.x);
        acc.y = fmaf(v, f.y, acc.y);
    }
    if (j < e && half == 0) {  // odd tail edge
        int2 q = edges[j];
        float2 f = __half22float2(Eh2[(size_t)q.x * 32 + l32]);
        float v = __int_as_float(q.y);
        acc.x = fmaf(v, f.x, acc.x);
        acc.y = fmaf(v, f.y, acc.y);
    }
    acc.x += __shfl_xor(acc.x, 32);
    acc.y += __shfl_xor(acc.y, 32);
    if (half == 0) *(float2*)&Egc[(size_t)r * DIM + l32 * 2] = acc;
}

// MFMA transform: per wave, 16 rows x 64 outcols via 16x16x32 f16 MFMA.
//   side1=(E+G)@W1 + side2=(E*G)@W2 -> leaky_relu -> l2norm.
// A-frag: lane l holds A[row=l&15][k=(l>>4)*8+j]; B-frag: B[k=(l>>4)*8+j][col=l&15];
// C/D: col=lane&15, row=(lane>>4)*4+reg (measured, m89/m91).
// In-place on E (each wave reads only its own 16 rows); also writes f16 copy Eh.
__global__ __launch_bounds__(256) void k_xform(float* __restrict__ E,
                                               const float* __restrict__ G,
                                               __half* __restrict__ Eh,
                                               const float* __restrict__ W1,
                                               const float* __restrict__ W2) {
    int l = threadIdx.x & 63;
    int wv = threadIdx.x >> 6;
    int m = l & 15;
    int ko = (l >> 4) * 8;  // 0,8,16,24

    // W fragments: 4 n-tiles x 2 k-chunks x 2 mats, held in VGPRs (L1/L2-resident loads)
    half8 b1[4][2], b2[4][2];
#pragma unroll
    for (int t = 0; t < 4; t++)
#pragma unroll
        for (int c = 0; c < 2; c++)
#pragma unroll
            for (int jj = 0; jj < 8; jj++) {
                int k = c * 32 + ko + jj;
                b1[t][c][jj] = (_Float16)W1[k * DIM + t * 16 + m];
                b2[t][c][jj] = (_Float16)W2[k * DIM + t * 16 + m];
            }

    size_t base = (size_t)blockIdx.x * 64 + wv * 16;

    // A fragments: xa = e+g, xb = e*g for this wave's 16 rows
    half8 a1[2], a2[2];
#pragma unroll
    for (int c = 0; c < 2; c++) {
        const float* pe = &E[(base + m) * DIM + c * 32 + ko];
        const float* pg = &G[(base + m) * DIM + c * 32 + ko];
        float4 e0 = *(const float4*)pe, e1 = *(const float4*)(pe + 4);
        float4 g0 = *(const float4*)pg, g1 = *(const float4*)(pg + 4);
        a1[c][0] = (_Float16)(e0.x + g0.x); a2[c][0] = (_Float16)(e0.x * g0.x);
        a1[c][1] = (_Float16)(e0.y + g0.y); a2[c][1] = (_Float16)(e0.y * g0.y);
        a1[c][2] = (_Float16)(e0.z + g0.z); a2[c][2] = (_Float16)(e0.z * g0.z);
        a1[c][3] = (_Float16)(e0.w + g0.w); a2[c][3] = (_Float16)(e0.w * g0.w);
        a1[c][4] = (_Float16)(e1.x + g1.x); a2[c][4] = (_Float16)(e1.x * g1.x);
        a1[c][5] = (_Float16)(e1.y + g1.y); a2[c][5] = (_Float16)(e1.y * g1.y);
        a1[c][6] = (_Float16)(e1.z + g1.z); a2[c][6] = (_Float16)(e1.z * g1.z);
        a1[c][7] = (_Float16)(e1.w + g1.w); a2[c][7] = (_Float16)(e1.w * g1.w);
    }

    f32x4 acc[4];
#pragma unroll
    for (int t = 0; t < 4; t++) {
        acc[t] = (f32x4){0.f, 0.f, 0.f, 0.f};
        acc[t] = __builtin_amdgcn_mfma_f32_16x16x32_f16(a1[0], b1[t][0], acc[t], 0, 0, 0);
        acc[t] = __builtin_amdgcn_mfma_f32_16x16x32_f16(a1[1], b1[t][1], acc[t], 0, 0, 0);
        acc[t] = __builtin_amdgcn_mfma_f32_16x16x32_f16(a2[0], b2[t][0], acc[t], 0, 0, 0);
        acc[t] = __builtin_amdgcn_mfma_f32_16x16x32_f16(a2[1], b2[t][1], acc[t], 0, 0, 0);
    }

    // epilogue: leaky-relu, per-row l2 norm (row = (l>>4)*4 + q, 16 lanes per row)
    float vv[4][4];
    float part[4];
#pragma unroll
    for (int q = 0; q < 4; q++) part[q] = 0.f;
#pragma unroll
    for (int t = 0; t < 4; t++)
#pragma unroll
        for (int q = 0; q < 4; q++) {
            float v = acc[t][q];
            v = v > 0.f ? v : NEG_SLOPE * v;
            vv[t][q] = v;
            part[q] = fmaf(v, v, part[q]);
        }
#pragma unroll
    for (int q = 0; q < 4; q++) {
#pragma unroll
        for (int off = 1; off < 16; off <<= 1) part[q] += __shfl_xor(part[q], off);
        part[q] = fmaxf(sqrtf(part[q]), 1e-12f);
    }
#pragma unroll
    for (int t = 0; t < 4; t++)
#pragma unroll
        for (int q = 0; q < 4; q++) {
            float o = vv[t][q] / part[q];
            size_t row = base + (l >> 4) * 4 + q;
            E[row * DIM + t * 16 + m] = o;
            Eh[row * DIM + t * 16 + m] = __float2half(o);
        }
}

// gather batch rows into u/i feature blocks
__global__ void k_gather(const float* __restrict__ E, const int* __restrict__ uids,
                         const int* __restrict__ iids, float* __restrict__ uf,
                         float* __restrict__ inf, int col0) {
    int gid = blockIdx.x * blockDim.x + threadIdx.x;
    int row = gid >> 6, lane = gid & 63;
    if (row < BATCH) {
        uf[row * 256 + col0 + lane] = E[(size_t)uids[row] * DIM + lane];
    } else if (row < 2 * BATCH) {
        int r = row - BATCH;
        inf[r * 256 + col0 + lane] = E[(size_t)(N_USERS + iids[r]) * DIM + lane];
    }
}

// ---------------- final scores: out = U @ I^T ----------------

__global__ __launch_bounds__(256) void k_score(const float* __restrict__ uf,
                                               const float* __restrict__ inf,
                                               float* __restrict__ out) {
    __shared__ float su[32][68];
    __shared__ float si[32][68];
    int t = threadIdx.x;
    int bx = blockIdx.x & 15, by = blockIdx.x >> 4;
    int tx = t & 15, ty = t >> 4;
    int lrow = t >> 2;
    int lk = (t & 3) * 8;
    float acc[4][4] = {};
    for (int kk = 0; kk < 256; kk += 32) {
        float4 a0 = *(const float4*)&uf[(by * 64 + lrow) * 256 + kk + lk];
        float4 a1 = *(const float4*)&uf[(by * 64 + lrow) * 256 + kk + lk + 4];
        float4 b0 = *(const float4*)&inf[(bx * 64 + lrow) * 256 + kk + lk];
        float4 b1 = *(const float4*)&inf[(bx * 64 + lrow) * 256 + kk + lk + 4];
        __syncthreads();
        su[lk + 0][lrow] = a0.x; su[lk + 1][lrow] = a0.y;
        su[lk + 2][lrow] = a0.z; su[lk + 3][lrow] = a0.w;
        su[lk + 4][lrow] = a1.x; su[lk + 5][lrow] = a1.y;
        su[lk + 6][lrow] = a1.z; su[lk + 7][lrow] = a1.w;
        si[lk + 0][lrow] = b0.x; si[lk + 1][lrow] = b0.y;
        si[lk + 2][lrow] = b0.z; si[lk + 3][lrow] = b0.w;
        si[lk + 4][lrow] = b1.x; si[lk + 5][lrow] = b1.y;
        si[lk + 6][lrow] = b1.z; si[lk + 7][lrow] = b1.w;
        __syncthreads();
#pragma unroll
        for (int k = 0; k < 32; k++) {
            const float* pu = &su[k][ty * 4];
            const float* pi = &si[k][tx * 4];
#pragma unroll
            for (int mi = 0; mi < 4; mi++)
#pragma unroll
                for (int ni = 0; ni < 4; ni++)
                    acc[mi][ni] = fmaf(pu[mi], pi[ni], acc[mi][ni]);
        }
    }
#pragma unroll
    for (int mi = 0; mi < 4; mi++)
#pragma unroll
        for (int ni = 0; ni < 4; ni++)
            out[(size_t)(by * 64 + ty * 4 + mi) * 1024 + bx * 64 + tx * 4 + ni] = acc[mi][ni];
}

// ---------------- launch ----------------

extern "C" void kernel_launch(void* const* d_in, const int* in_sizes, int n_in,
                              void* d_out, int out_size, void* d_ws, size_t ws_size,
                              hipStream_t stream) {
    const float* user_embed = (const float*)d_in[0];
    const float* item_embed = (const float*)d_in[1];
    const float* W1[3] = {(const float*)d_in[2], (const float*)d_in[3], (const float*)d_in[4]};
    const float* W2[3] = {(const float*)d_in[5], (const float*)d_in[6], (const float*)d_in[7]};
    const float* adj_vals = (const float*)d_in[8];
    const int* adj_rows = (const int*)d_in[9];
    const int* adj_cols = (const int*)d_in[10];
    const int* user_ids = (const int*)d_in[11];
    const int* item_ids = (const int*)d_in[12];
    float* out = (float*)d_out;

    // workspace carve-up (all 16B-aligned)
    float* E = (float*)d_ws;                         // NPAD*64 f32
    float* Egc = E + (size_t)NPAD * DIM;             // NPAD*64 f32
    __half* Eh = (__half*)(Egc + (size_t)NPAD * DIM);// NPAD*64 f16
    float* uf = (float*)(Eh + (size_t)NPAD * DIM);   // 256K f32
    float* inf = uf + BATCH * 256;                   // 256K f32
    int2* edges = (int2*)(inf + BATCH * 256);        // 1.2M int2
    int* row_ptr = (int*)(edges + NNZ);              // 100001
    int* cursors = row_ptr + (N_NODES + 1);          // 100000
    int* counts = cursors + N_NODES;                 // 100000
    int* blk = counts + N_NODES;                     // 128

    const int NBLK = (N_NODES + 1023) / 1024;  // 98

    // CSR build
    k_zero<<<(N_NODES + 255) / 256, 256, 0, stream>>>(counts, N_NODES);
    k_count<<<1024, 256, 0, stream>>>(adj_rows, counts);
    k_scanA<<<NBLK, 256, 0, stream>>>(counts, blk);
    k_scanB<<<1, 128, 0, stream>>>(blk, NBLK, row_ptr);
    k_scanC<<<NBLK, 256, 0, stream>>>(counts, blk, row_ptr, cursors);
    k_scatter<<<1024, 256, 0, stream>>>(adj_rows, adj_cols, adj_vals, cursors, edges);

    // E init (f32 + f16 copy) + layer-0 gather
    k_initE<<<(N_NODES * DIM / 4 + 255) / 256, 256, 0, stream>>>(
        (const float4*)user_embed, (const float4*)item_embed, (float4*)E, (__half2*)Eh);
    k_gather<<<(2 * BATCH * DIM) / 256, 256, 0, stream>>>(E, user_ids, item_ids, uf, inf, 0);

    // 3 propagation layers: spmm(f16 gathers) -> MFMA transform (in-place, updates Eh)
    for (int l = 0; l < 3; l++) {
        k_spmm<<<(N_NODES * DIM) / 256, 256, 0, stream>>>((const __half2*)Eh, row_ptr, edges, Egc);
        k_xform<<<NPAD / 64, 256, 0, stream>>>(E, Egc, Eh, W1[l], W2[l]);
        k_gather<<<(2 * BATCH * DIM) / 256, 256, 0, stream>>>(E, user_ids, item_ids, uf, inf,
                                                              (l + 1) * 64);
    }

    // scores
    k_score<<<256, 256, 0, stream>>>(uf, inf, out);
}